// Round 4
// baseline (116.727 us; speedup 1.0000x reference)
//
#include <hip/hip_runtime.h>

namespace {

constexpr int Hh   = 256;
constexpr int Ww   = 256;
constexpr int IMG  = Hh * Ww;            // 65536
constexpr int NV   = (Hh - 1) * Ww;      // 65280 vertical candidates
constexpr int NC   = NV + Hh * (Ww - 1); // 130560 total candidates
constexpr int PMAX = 8192;
constexpr int CB   = 256;                // candidate block
constexpr int NCB  = (NC + CB - 1) / CB; // 510
constexpr int NB   = 4;                  // batch
constexpr int NIMG = 2 * NB;             // 8 images (pred 0..3, gt 4..7)
constexpr float EPSF = 1e-8f;
constexpr int TCH  = 8;                  // chamfer target chunks
constexpr int CHK  = PMAX / TCH;         // 1024 max targets per chunk (8 KB LDS)

// Candidate c -> (point, valid). Order matches reference: vertical block
// (row-major over (H-1)xW) then horizontal block (row-major over Hx(W-1)).
// NOTE: compaction order is NOT preserved (wave-atomic ranks). Valid because
// chamfer min / means are order-invariant over the point set, and actual
// valid counts (~2k) are far below PMAX so no truncation occurs.
__device__ inline bool cand_pt(const float* img, int c, float2& pt) {
  if (c < NV) {
    int i = c >> 8, j = c & 255;             // W == 256
    float v1 = img[i * Ww + j];
    float v2 = img[(i + 1) * Ww + j];
    bool valid = (v1 == 0.f) | (v2 == 0.f) | (v1 * v2 < 0.f);
    float a = fabsf(v1) / (fabsf(v1) + fabsf(v2) + EPSF);
    float row = (v1 == 0.f) ? (float)i
              : ((v2 == 0.f) ? (float)(i + 1) : (float)i + a);
    pt.x = row; pt.y = (float)j;
    return valid;
  } else {
    int cc = c - NV;
    int i = cc / (Ww - 1);
    int j = cc - i * (Ww - 1);
    float h1 = img[i * Ww + j];
    float h2 = img[i * Ww + j + 1];
    bool valid = (h1 == 0.f) | (h2 == 0.f) | (h1 * h2 < 0.f);
    float a = fabsf(h1) / (fabsf(h1) + fabsf(h2) + EPSF);
    float col = (h1 == 0.f) ? (float)j
              : ((h2 == 0.f) ? (float)(j + 1) : (float)j + a);
    pt.x = (float)i; pt.y = col;
    return valid;
  }
}

__device__ inline const float* img_ptr(const float* pred, const float* gt, int img) {
  return (img < NB) ? pred + img * IMG : gt + (img - NB) * IMG;
}

// Kernel 1: zero the accumulator words (cheaper than a rocclr fill dispatch).
__global__ void init_kernel(int* __restrict__ counts, float* __restrict__ sdfsums) {
  if (threadIdx.x < NIMG) counts[threadIdx.x] = 0;
  if (threadIdx.x < NB)   sdfsums[threadIdx.x] = 0.f;
}

// Kernel 2: fused extract = minq re-init + candidate eval + wave-atomic
// compaction + L1 |pred-gt| block partial -> atomicAdd.
__global__ void extract_kernel(const float* __restrict__ pred,
                               const float* __restrict__ gt,
                               int* __restrict__ counts,
                               float* __restrict__ sdfsums,
                               float2* __restrict__ pts,
                               unsigned int* __restrict__ minq) {
  int img = blockIdx.y;
  const float* im = img_ptr(pred, gt, img);
  int c = blockIdx.x * CB + threadIdx.x;

  // fused: re-init minq (combo index space == img index space, 8*8192)
  if (blockIdx.x < PMAX / CB)
    minq[img * PMAX + c] = 0x7F7F7F7Fu;          // ~3.39e38 as float

  bool valid = false;
  float2 pt;
  if (c < NC) valid = cand_pt(im, c, pt);
  unsigned long long b = __ballot(valid);
  int lane = threadIdx.x & 63, wid = threadIdx.x >> 6;

  int base = 0;
  if (lane == 0 && b)
    base = atomicAdd(&counts[img], __popcll(b));   // one atomic per wave
  base = __shfl(base, 0, 64);
  if (valid) {
    int rank = base + __popcll(b & ((1ull << lane) - 1ull));
    if (rank < PMAX) pts[img * PMAX + rank] = pt;
  }

  // fused L1 (pred images only; pixel blocks only; c < IMG guaranteed)
  if (img < NB && blockIdx.x < IMG / CB) {
    float v = fabsf(pred[img * IMG + c] - gt[img * IMG + c]);
    for (int off = 32; off > 0; off >>= 1) v += __shfl_down(v, off, 64);
    __shared__ float wred[CB / 64];
    if (lane == 0) wred[wid] = v;
    __syncthreads();
    if (threadIdx.x == 0)
      atomicAdd(&sdfsums[img], wred[0] + wred[1] + wred[2] + wred[3]);
  }
}

__device__ inline void min_step(float2 p, float2 t, float& m) {
  float dx = p.x - t.x;
  float dy = p.y - t.y;
  m = fminf(m, dx * dx + dy * dy);
}

// Kernel 3: partial chamfer. grid = (PMAX/256 qblocks, TCH tchunks, 2*NB).
// Each block: partial min^2 over its target chunk for its 256 queries,
// merged via uint atomicMin (valid: d2 >= 0 so IEEE bits are monotone).
__global__ void chamfer_kernel(const float2* __restrict__ pts,
                               const int* __restrict__ counts,
                               unsigned int* __restrict__ minq) {
  int b   = blockIdx.z & (NB - 1);
  int dir = blockIdx.z / NB;
  int qimg = (dir == 0) ? b : NB + b;
  int timg = (dir == 0) ? NB + b : b;
  int nq = min(counts[qimg], PMAX), nt = min(counts[timg], PMAX);
  if (nq == 0 || nt == 0) return;                  // block-uniform
  int qbase = blockIdx.x * 256;
  if (qbase >= nq) return;
  int len = (nt + TCH - 1) / TCH;
  int ts  = blockIdx.y * len;
  if (ts >= nt) return;
  int cnt = min(len, nt - ts);

  __shared__ float2 tgt[CHK];
  for (int t = threadIdx.x; t < cnt; t += 256)
    tgt[t] = pts[timg * PMAX + ts + t];
  __syncthreads();

  int q = qbase + threadIdx.x;
  float2 p = (q < nq) ? pts[qimg * PMAX + q] : make_float2(0.f, 0.f);
  float m0 = 3.4e38f, m1 = 3.4e38f, m2 = 3.4e38f, m3 = 3.4e38f;
  int j = 0;
  for (; j + 4 <= cnt; j += 4) {                   // 4 independent min chains
    min_step(p, tgt[j + 0], m0);
    min_step(p, tgt[j + 1], m1);
    min_step(p, tgt[j + 2], m2);
    min_step(p, tgt[j + 3], m3);
  }
  for (; j < cnt; ++j) min_step(p, tgt[j], m0);
  float m = fminf(fminf(m0, m1), fminf(m2, m3));

  if (q < nq)
    atomicMin(&minq[(dir * NB + b) * PMAX + q], __float_as_uint(m));
}

// Kernel 4: single-block tail = per-combo sqrt-sum reduce + final combine.
__global__ void tail_kernel(const unsigned int* __restrict__ minq,
                            const int* __restrict__ counts,
                            const float* __restrict__ sdfsums,
                            float* __restrict__ out) {
  __shared__ float csum[NIMG];
  __shared__ float wsum[4];
  int lane = threadIdx.x & 63, wid = threadIdx.x >> 6;
  for (int combo = 0; combo < NIMG; ++combo) {
    int dir = combo / NB, b = combo & (NB - 1);
    int qimg = (dir == 0) ? b : NB + b;
    int nq = min(counts[qimg], PMAX);
    float s = 0.f;
    for (int q = threadIdx.x; q < nq; q += 256)
      s += sqrtf(__uint_as_float(minq[combo * PMAX + q]));
    for (int off = 32; off > 0; off >>= 1) s += __shfl_down(s, off, 64);
    if (lane == 0) wsum[wid] = s;
    __syncthreads();
    if (threadIdx.x == 0) csum[combo] = wsum[0] + wsum[1] + wsum[2] + wsum[3];
    __syncthreads();
  }
  if (threadIdx.x == 0) {
    float total = 0.f;
    for (int b = 0; b < NB; ++b) {
      float n1 = (float)min(counts[b], PMAX);
      float n2 = (float)min(counts[NB + b], PMAX);
      float mean1 = csum[b]      / fmaxf(n1, 1.f);
      float mean2 = csum[NB + b] / fmaxf(n2, 1.f);
      float cd = -mean1 + mean2;
      float ch = (n1 > 0.f && n2 > 0.f) ? fabsf(cd) : 0.f;
      total += ch + sdfsums[b] * (1.f / (float)IMG);
    }
    out[0] = total * (1.f / (float)NB);
  }
}

} // namespace

extern "C" void kernel_launch(void* const* d_in, const int* in_sizes, int n_in,
                              void* d_out, int out_size, void* d_ws, size_t ws_size,
                              hipStream_t stream) {
  const float* pred = (const float*)d_in[0];
  const float* gt   = (const float*)d_in[1];
  float* out = (float*)d_out;

  char* ws = (char*)d_ws;
  // layout (bytes):
  //   [32,48)      float sdfsums[4]     (zeroed by init_kernel)
  //   [64,96)      int counts[8]        (zeroed by init_kernel)
  //   [32768,+524288)  float2 pts[8*8192]
  //   [557056,+262144) uint minq[8*8192]   (re-init in extract_kernel)
  float*        sdfsums = (float*)(ws + 32);
  int*          counts  = (int*)(ws + 64);
  float2*       pts     = (float2*)(ws + 32768);
  unsigned int* minq    = (unsigned int*)(ws + 557056);

  init_kernel<<<1, 64, 0, stream>>>(counts, sdfsums);
  extract_kernel<<<dim3(NCB, NIMG), CB, 0, stream>>>(pred, gt, counts, sdfsums,
                                                     pts, minq);
  chamfer_kernel<<<dim3(PMAX / 256, TCH, NIMG), 256, 0, stream>>>(pts, counts, minq);
  tail_kernel<<<1, 256, 0, stream>>>(minq, counts, sdfsums, out);
}